// Round 6
// baseline (86.075 us; speedup 1.0000x reference)
//
#include <hip/hip_runtime.h>

#define BB 4
#define SS 8192
#define DD 1024
#define TPB 256
#define EPT 32            // boundary elements per thread = SS / TPB
#define MAGIC 0x13579BDFu

typedef float vf4 __attribute__((ext_vector_type(4)));

// Single-dispatch producer/consumer:
//  blocks [0, BB)        : per-batch stable-partition scan -> sel + ntok, then
//                          publish device-scope flag.
//  blocks [BB, BB+ncons) : poll flag, then gather 8 output rows (2 per wave).
// All blocks are co-resident (grid <= HW capacity), so the spin cannot deadlock
// regardless of dispatch order.
__global__ __launch_bounds__(TPB) void chunk_onepass(const void* __restrict__ bptr,
                                                     const float* __restrict__ x,
                                                     float* __restrict__ out,
                                                     float* __restrict__ ntok,
                                                     int* __restrict__ sel,
                                                     unsigned int* __restrict__ flags,
                                                     int max_chunks, int nrows) {
    const int t = threadIdx.x;

    if (blockIdx.x < BB) {
        // ---------------- producer ----------------
        const int b = blockIdx.x;

        // dtype detect over 16 KB window: 0=int32, 1=byte-bool, 2=float32
        __shared__ int s_non, s_mis;
        if (t == 0) { s_non = 0; s_mis = 0; }
        __syncthreads();
        {
            const uint4* __restrict__ wp = (const uint4*)bptr;
            unsigned int accN = 0, accM = 0;
            #pragma unroll
            for (int r = 0; r < 4; ++r) {            // 256*4 uint4 = 16 KB
                uint4 w = wp[t + r * TPB];
                unsigned int o = w.x | w.y | w.z | w.w;
                accN |= o & 0xFEFEFEFEu;             // any byte > 1  -> float32
                accM |= o & 0xFFFFFF00u;             // misaligned nonzero -> byte bool
            }
            if (accN) atomicOr(&s_non, 1);
            if (accM) atomicOr(&s_mis, 1);
        }
        __syncthreads();
        const int f = s_non ? 2 : (s_mis ? 1 : 0);

        // 32 boundary elements per thread -> bitmask
        unsigned int mask = 0;
        if (f == 0) {
            const int4* __restrict__ p = (const int4*)((const int*)bptr + b * SS);
            #pragma unroll
            for (int r = 0; r < 8; ++r) {
                int4 w = p[t * 8 + r];
                mask |= (unsigned int)((w.x != 0) | ((w.y != 0) << 1) |
                                       ((w.z != 0) << 2) | ((w.w != 0) << 3)) << (r * 4);
            }
        } else if (f == 1) {
            const uint4* __restrict__ p = (const uint4*)((const unsigned char*)bptr + b * SS);
            uint4 w0 = p[t * 2], w1 = p[t * 2 + 1];
            unsigned int ws[8] = {w0.x, w0.y, w0.z, w0.w, w1.x, w1.y, w1.z, w1.w};
            #pragma unroll
            for (int q = 0; q < 8; ++q) {
                unsigned int v = ws[q];
                mask |= (unsigned int)(((v & 0xFFu) != 0u) |
                                       ((((v >> 8) & 0xFFu) != 0u) << 1) |
                                       ((((v >> 16) & 0xFFu) != 0u) << 2) |
                                       ((((v >> 24) & 0xFFu) != 0u) << 3)) << (q * 4);
            }
        } else {
            const float4* __restrict__ p = (const float4*)((const float*)bptr + b * SS);
            #pragma unroll
            for (int r = 0; r < 8; ++r) {
                float4 w = p[t * 8 + r];
                mask |= (unsigned int)((w.x != 0.0f) | ((w.y != 0.0f) << 1) |
                                       ((w.z != 0.0f) << 2) | ((w.w != 0.0f) << 3)) << (r * 4);
            }
        }
        const int cnt = __popc(mask);

        // wave scan + block combine (4 waves)
        const int lane = t & 63;
        const int wave = t >> 6;
        int scan = cnt;
        #pragma unroll
        for (int o = 1; o < 64; o <<= 1) {
            int n = __shfl_up(scan, o, 64);
            if (lane >= o) scan += n;
        }
        __shared__ int waveTot[4];
        __shared__ int waveOff[4];
        __shared__ int s_total;
        if (lane == 63) waveTot[wave] = scan;
        __syncthreads();
        if (t == 0) {
            int acc = 0;
            #pragma unroll
            for (int w = 0; w < 4; ++w) { waveOff[w] = acc; acc += waveTot[w]; }
            s_total = acc;
        }
        __syncthreads();
        const int T = s_total;

        int tr = waveOff[wave] + (scan - cnt);   // exclusive prefix of trues
        #pragma unroll
        for (int k = 0; k < EPT; ++k) {
            const int j = t * EPT + k;
            int dest;
            if ((mask >> k) & 1u) { dest = tr; tr++; }
            else                  { dest = T + (j - tr); }
            if (dest < max_chunks) sel[b * max_chunks + dest] = j;
        }
        if (t == 0) ntok[b] = (float)T;

        __syncthreads();       // all sel stores drained (vmcnt(0) before barrier)
        __threadfence();       // flush to device coherence point
        if (t == 0)
            __hip_atomic_store(&flags[b], MAGIC, __ATOMIC_RELEASE, __HIP_MEMORY_SCOPE_AGENT);
    } else {
        // ---------------- consumer ----------------
        const int cb = blockIdx.x - BB;
        const int wave = t >> 6;
        const int lane = t & 63;
        const long long row0 = (long long)cb * 8 + wave * 2;

        // wait for the (at most 2) batches this block's 8 rows touch
        if (t == 0) {
            const long long rA = (long long)cb * 8;
            long long rB = rA + 7; if (rB >= nrows) rB = nrows - 1;
            const int bA = (int)(rA / max_chunks);
            const int bZ = (int)(rB / max_chunks);
            while (__hip_atomic_load(&flags[bA], __ATOMIC_ACQUIRE, __HIP_MEMORY_SCOPE_AGENT) != MAGIC)
                __builtin_amdgcn_s_sleep(2);
            if (bZ != bA)
                while (__hip_atomic_load(&flags[bZ], __ATOMIC_ACQUIRE, __HIP_MEMORY_SCOPE_AGENT) != MAGIC)
                    __builtin_amdgcn_s_sleep(2);
        }
        __syncthreads();
        __threadfence();       // acquire: invalidate stale cached sel lines

        if (row0 >= nrows) return;
        const long long row1 = row0 + 1;
        const bool has1 = (row1 < nrows);

        const int b0 = (int)(row0 / max_chunks);
        const int j0 = sel[row0];
        const vf4* __restrict__ s0 = (const vf4*)(x + ((long long)b0 * SS + j0) * DD);
        vf4* __restrict__ d0 = (vf4*)(out + row0 * (long long)DD);

        const int b1 = has1 ? (int)(row1 / max_chunks) : b0;
        const int j1 = has1 ? sel[row1] : j0;
        const vf4* __restrict__ s1 = (const vf4*)(x + ((long long)b1 * SS + j1) * DD);
        vf4* __restrict__ d1 = (vf4*)(out + row1 * (long long)DD);

        vf4 a0 = s0[lane], a1 = s0[lane + 64], a2 = s0[lane + 128], a3 = s0[lane + 192];
        vf4 c0 = s1[lane], c1 = s1[lane + 64], c2 = s1[lane + 128], c3 = s1[lane + 192];

        d0[lane] = a0; d0[lane + 64] = a1; d0[lane + 128] = a2; d0[lane + 192] = a3;
        if (has1) {
            d1[lane] = c0; d1[lane + 64] = c1; d1[lane + 128] = c2; d1[lane + 192] = c3;
        }
    }
}

// Fallback gather (two-dispatch path) for shapes where the one-pass grid would
// exceed guaranteed co-residency.
__global__ __launch_bounds__(TPB) void gather_rows(const float* __restrict__ x,
                                                   const int* __restrict__ sel,
                                                   float* __restrict__ out,
                                                   int max_chunks, int nrows) {
    const int wave = threadIdx.x >> 6;
    const int lane = threadIdx.x & 63;
    const long long row0 = (long long)blockIdx.x * 8 + wave * 2;
    if (row0 >= nrows) return;
    const long long row1 = row0 + 1;
    const bool has1 = (row1 < nrows);
    const int b0 = (int)(row0 / max_chunks);
    const int j0 = sel[row0];
    const vf4* __restrict__ s0 = (const vf4*)(x + ((long long)b0 * SS + j0) * DD);
    vf4* __restrict__ d0 = (vf4*)(out + row0 * (long long)DD);
    const int b1 = has1 ? (int)(row1 / max_chunks) : b0;
    const int j1 = has1 ? sel[row1] : j0;
    const vf4* __restrict__ s1 = (const vf4*)(x + ((long long)b1 * SS + j1) * DD);
    vf4* __restrict__ d1 = (vf4*)(out + row1 * (long long)DD);
    vf4 a0 = s0[lane], a1 = s0[lane + 64], a2 = s0[lane + 128], a3 = s0[lane + 192];
    vf4 c0 = s1[lane], c1 = s1[lane + 64], c2 = s1[lane + 128], c3 = s1[lane + 192];
    d0[lane] = a0; d0[lane + 64] = a1; d0[lane + 128] = a2; d0[lane + 192] = a3;
    if (has1) {
        d1[lane] = c0; d1[lane + 64] = c1; d1[lane + 128] = c2; d1[lane + 192] = c3;
    }
}

extern "C" void kernel_launch(void* const* d_in, const int* in_sizes, int n_in,
                              void* d_out, int out_size, void* d_ws, size_t ws_size,
                              hipStream_t stream) {
    const float* x = (const float*)d_in[0];
    const void* bptr = d_in[1];
    float* out = (float*)d_out;

    const int max_chunks = (out_size - BB) / (BB * DD);
    const int nrows = BB * max_chunks;
    const int ncons = (nrows + 7) / 8;

    const size_t selBytes = (size_t)BB * max_chunks * sizeof(int);
    int* sel = (int*)d_ws;
    unsigned int* flags = (unsigned int*)((char*)d_ws + ((selBytes + 255) & ~(size_t)255));
    float* ntok = out + (long long)nrows * DD;

    if (BB + ncons <= 1792) {
        // single dispatch: producers + consumers co-resident
        chunk_onepass<<<BB + ncons, TPB, 0, stream>>>(bptr, x, out, ntok, sel, flags,
                                                      max_chunks, nrows);
    } else {
        // fallback: producers alone, then gather
        chunk_onepass<<<BB, TPB, 0, stream>>>(bptr, x, out, ntok, sel, flags,
                                              max_chunks, nrows);
        gather_rows<<<ncons, TPB, 0, stream>>>(x, sel, out, max_chunks, nrows);
    }
}

// Round 7
// 22.214 us; speedup vs baseline: 3.8747x; 3.8747x over previous
//
#include <hip/hip_runtime.h>

#define BB 4
#define SS 8192
#define DD 1024
#define TPB 256
#define EPT 32            // boundary elements per thread = SS / TPB

typedef float vf4 __attribute__((ext_vector_type(4)));

// Kernel A: one 256-thread block per batch. Dtype-detect (16 KB window),
// bitmask scan (32 elems/thread), scatter sel, write num_tokens.
__global__ __launch_bounds__(TPB) void build_sel(const void* __restrict__ bptr,
                                                 int* __restrict__ sel,
                                                 float* __restrict__ ntok,
                                                 int max_chunks) {
    const int b = blockIdx.x;
    const int t = threadIdx.x;

    // dtype detect: 0=int32, 1=byte-bool, 2=float32
    __shared__ int s_non, s_mis;
    if (t == 0) { s_non = 0; s_mis = 0; }
    __syncthreads();
    {
        const uint4* __restrict__ wp = (const uint4*)bptr;
        unsigned int accN = 0, accM = 0;
        #pragma unroll
        for (int r = 0; r < 4; ++r) {                // 256*4 uint4 = 16 KB
            uint4 w = wp[t + r * TPB];
            unsigned int o = w.x | w.y | w.z | w.w;
            accN |= o & 0xFEFEFEFEu;                 // any byte > 1  -> float32
            accM |= o & 0xFFFFFF00u;                 // misaligned nonzero -> byte bool
        }
        if (accN) atomicOr(&s_non, 1);
        if (accM) atomicOr(&s_mis, 1);
    }
    __syncthreads();
    const int f = s_non ? 2 : (s_mis ? 1 : 0);

    // 32 boundary elements per thread -> bitmask
    unsigned int mask = 0;
    if (f == 0) {
        const int4* __restrict__ p = (const int4*)((const int*)bptr + b * SS);
        #pragma unroll
        for (int r = 0; r < 8; ++r) {
            int4 w = p[t * 8 + r];
            mask |= (unsigned int)((w.x != 0) | ((w.y != 0) << 1) |
                                   ((w.z != 0) << 2) | ((w.w != 0) << 3)) << (r * 4);
        }
    } else if (f == 1) {
        const uint4* __restrict__ p = (const uint4*)((const unsigned char*)bptr + b * SS);
        uint4 w0 = p[t * 2], w1 = p[t * 2 + 1];
        unsigned int ws[8] = {w0.x, w0.y, w0.z, w0.w, w1.x, w1.y, w1.z, w1.w};
        #pragma unroll
        for (int q = 0; q < 8; ++q) {
            unsigned int v = ws[q];
            mask |= (unsigned int)(((v & 0xFFu) != 0u) |
                                   ((((v >> 8) & 0xFFu) != 0u) << 1) |
                                   ((((v >> 16) & 0xFFu) != 0u) << 2) |
                                   ((((v >> 24) & 0xFFu) != 0u) << 3)) << (q * 4);
        }
    } else {
        const float4* __restrict__ p = (const float4*)((const float*)bptr + b * SS);
        #pragma unroll
        for (int r = 0; r < 8; ++r) {
            float4 w = p[t * 8 + r];
            mask |= (unsigned int)((w.x != 0.0f) | ((w.y != 0.0f) << 1) |
                                   ((w.z != 0.0f) << 2) | ((w.w != 0.0f) << 3)) << (r * 4);
        }
    }
    const int cnt = __popc(mask);

    // wave scan + 4-wave combine
    const int lane = t & 63;
    const int wave = t >> 6;
    int scan = cnt;
    #pragma unroll
    for (int o = 1; o < 64; o <<= 1) {
        int n = __shfl_up(scan, o, 64);
        if (lane >= o) scan += n;
    }
    __shared__ int waveTot[4];
    __shared__ int waveOff[4];
    __shared__ int s_total;
    if (lane == 63) waveTot[wave] = scan;
    __syncthreads();
    if (t == 0) {
        int acc = 0;
        #pragma unroll
        for (int w = 0; w < 4; ++w) { waveOff[w] = acc; acc += waveTot[w]; }
        s_total = acc;
    }
    __syncthreads();
    const int T = s_total;

    int tr = waveOff[wave] + (scan - cnt);   // exclusive prefix of trues
    #pragma unroll
    for (int k = 0; k < EPT; ++k) {
        const int j = t * EPT + k;
        int dest;
        if ((mask >> k) & 1u) { dest = tr; tr++; }
        else                  { dest = T + (j - tr); }
        if (dest < max_chunks) sel[b * max_chunks + dest] = j;
    }
    if (t == 0) ntok[b] = (float)T;
}

// Kernel B: 4 rows per wave, 16 rows per 256-thread block.
// 16 float4 loads in flight, then 16 stores — latency-tolerant for L3-hit reads.
__global__ __launch_bounds__(TPB) void gather_rows(const float* __restrict__ x,
                                                   const int* __restrict__ sel,
                                                   float* __restrict__ out,
                                                   int max_chunks, int nrows) {
    const int wave = threadIdx.x >> 6;
    const int lane = threadIdx.x & 63;
    const long long rb = (long long)blockIdx.x * 16 + wave * 4;

    const vf4* src[4];
    vf4* dst[4];
    bool valid[4];
    #pragma unroll
    for (int r = 0; r < 4; ++r) {
        const long long row = rb + r;
        valid[r] = row < nrows;
        const long long rc = valid[r] ? row : (nrows - 1);
        const int b = (int)(rc / max_chunks);
        const int j = sel[rc];
        src[r] = (const vf4*)(x + ((long long)b * SS + j) * DD);
        dst[r] = (vf4*)(out + rc * (long long)DD);
    }

    vf4 v[4][4];
    #pragma unroll
    for (int r = 0; r < 4; ++r)
        #pragma unroll
        for (int q = 0; q < 4; ++q)
            v[r][q] = src[r][lane + 64 * q];

    #pragma unroll
    for (int r = 0; r < 4; ++r)
        if (valid[r])
            #pragma unroll
            for (int q = 0; q < 4; ++q)
                dst[r][lane + 64 * q] = v[r][q];
}

extern "C" void kernel_launch(void* const* d_in, const int* in_sizes, int n_in,
                              void* d_out, int out_size, void* d_ws, size_t ws_size,
                              hipStream_t stream) {
    const float* x = (const float*)d_in[0];
    const void* bptr = d_in[1];
    float* out = (float*)d_out;

    const int max_chunks = (out_size - BB) / (BB * DD);
    const int nrows = BB * max_chunks;

    int* sel = (int*)d_ws;
    float* ntok = out + (long long)nrows * DD;

    build_sel<<<BB, TPB, 0, stream>>>(bptr, sel, ntok, max_chunks);
    gather_rows<<<(nrows + 15) / 16, TPB, 0, stream>>>(x, sel, out, max_chunks, nrows);
}

// Round 8
// 18.373 us; speedup vs baseline: 4.6849x; 1.2091x over previous
//
#include <hip/hip_runtime.h>

#define BB 4
#define SS 8192
#define DD 1024
#define TPB 1024
#define GROUP 64          // output rows per block

typedef float vf4 __attribute__((ext_vector_type(4)));

// Single dispatch. Each 1024-thread block owns 64 consecutive output rows of
// one batch: it recomputes the per-batch stable-partition scan (48 KB of
// L2-hot reads, amortized over a 256 KB copy), captures its 64 source rows,
// then copies them. No inter-kernel dependency, no device-scope sync.
__global__ __launch_bounds__(TPB) void chunk_block(const void* __restrict__ bptr,
                                                   const float* __restrict__ x,
                                                   float* __restrict__ out,
                                                   float* __restrict__ ntok,
                                                   int max_chunks, int ngroups) {
    const int b = blockIdx.x / ngroups;
    const int g = blockIdx.x % ngroups;
    const int row0 = g * GROUP;
    const int t = threadIdx.x;
    const int lane = t & 63;
    const int wave = t >> 6;

    // ---- dtype detect over 16 KB window: 0=int32, 1=byte-bool, 2=float32 ----
    __shared__ int s_non, s_mis;
    if (t == 0) { s_non = 0; s_mis = 0; }
    __syncthreads();
    {
        const uint4* __restrict__ wp = (const uint4*)bptr;   // 1024 uint4 = 16 KB
        uint4 w = wp[t];
        unsigned int o = w.x | w.y | w.z | w.w;
        if (o & 0xFEFEFEFEu) atomicOr(&s_non, 1);   // any byte > 1  -> float32
        if (o & 0xFFFFFF00u) atomicOr(&s_mis, 1);   // misaligned nonzero -> byte bool
    }
    __syncthreads();
    const int f = s_non ? 2 : (s_mis ? 1 : 0);

    // ---- boundaries: 8 elements per thread -> bitmask ----
    unsigned int mask = 0;
    if (f == 0) {
        const int4* __restrict__ p = (const int4*)((const int*)bptr + b * SS);
        int4 w0 = p[t * 2], w1 = p[t * 2 + 1];
        int vi[8] = {w0.x, w0.y, w0.z, w0.w, w1.x, w1.y, w1.z, w1.w};
        #pragma unroll
        for (int k = 0; k < 8; ++k) mask |= (unsigned int)(vi[k] != 0) << k;
    } else if (f == 1) {
        const uint2* __restrict__ p = (const uint2*)((const unsigned char*)bptr + b * SS);
        uint2 w = p[t];
        unsigned int ws[2] = {w.x, w.y};
        #pragma unroll
        for (int k = 0; k < 8; ++k)
            mask |= (unsigned int)(((ws[k >> 2] >> ((k & 3) * 8)) & 0xFFu) != 0u) << k;
    } else {
        const float4* __restrict__ p = (const float4*)((const float*)bptr + b * SS);
        float4 w0 = p[t * 2], w1 = p[t * 2 + 1];
        float vf[8] = {w0.x, w0.y, w0.z, w0.w, w1.x, w1.y, w1.z, w1.w};
        #pragma unroll
        for (int k = 0; k < 8; ++k) mask |= (unsigned int)(vf[k] != 0.0f) << k;
    }
    const int cnt = __popc(mask);

    // ---- wave scan + 16-wave combine ----
    int scan = cnt;
    #pragma unroll
    for (int o = 1; o < 64; o <<= 1) {
        int n = __shfl_up(scan, o, 64);
        if (lane >= o) scan += n;
    }
    __shared__ int waveTot[16];
    __shared__ int waveOff[16];
    __shared__ int s_total;
    __shared__ int s_rowj[GROUP];
    if (lane == 63) waveTot[wave] = scan;
    __syncthreads();
    if (t == 0) {
        int acc = 0;
        #pragma unroll
        for (int w = 0; w < 16; ++w) { waveOff[w] = acc; acc += waveTot[w]; }
        s_total = acc;
    }
    __syncthreads();
    const int T = s_total;

    // ---- dests; capture the 64 source rows this block owns ----
    int tr = waveOff[wave] + (scan - cnt);   // exclusive prefix of trues
    #pragma unroll
    for (int k = 0; k < 8; ++k) {
        const int j = t * 8 + k;
        int dest;
        if ((mask >> k) & 1u) { dest = tr; tr++; }
        else                  { dest = T + (j - tr); }
        const int rel = dest - row0;
        if ((unsigned)rel < (unsigned)GROUP) s_rowj[rel] = j;
    }
    if (g == 0 && t == 0) ntok[b] = (float)T;
    __syncthreads();

    // ---- copy: each of 16 waves moves 4 rows (4 KB each) ----
    const int rbase = wave * 4;
    const vf4* src[4];
    vf4* dst[4];
    bool valid[4];
    #pragma unroll
    for (int r = 0; r < 4; ++r) {
        const int c = row0 + rbase + r;
        valid[r] = c < max_chunks;
        const int cc = valid[r] ? c : 0;
        const int j = s_rowj[valid[r] ? (rbase + r) : 0];
        src[r] = (const vf4*)(x + ((long long)b * SS + j) * DD);
        dst[r] = (vf4*)(out + ((long long)b * max_chunks + cc) * (long long)DD);
    }
    vf4 v[4][4];
    #pragma unroll
    for (int r = 0; r < 4; ++r)
        #pragma unroll
        for (int q = 0; q < 4; ++q)
            v[r][q] = src[r][lane + 64 * q];
    #pragma unroll
    for (int r = 0; r < 4; ++r)
        if (valid[r])
            #pragma unroll
            for (int q = 0; q < 4; ++q)
                dst[r][lane + 64 * q] = v[r][q];
}

extern "C" void kernel_launch(void* const* d_in, const int* in_sizes, int n_in,
                              void* d_out, int out_size, void* d_ws, size_t ws_size,
                              hipStream_t stream) {
    const float* x = (const float*)d_in[0];
    const void* bptr = d_in[1];
    float* out = (float*)d_out;

    const int max_chunks = (out_size - BB) / (BB * DD);
    const int ngroups = (max_chunks + GROUP - 1) / GROUP;
    float* ntok = out + (long long)BB * max_chunks * DD;

    chunk_block<<<BB * ngroups, TPB, 0, stream>>>(bptr, x, out, ntok, max_chunks, ngroups);
}